// Round 9
// baseline (198.793 us; speedup 1.0000x reference)
//
#include <hip/hip_runtime.h>

// LSTM, B=4096, T=2048, IN=3, H=4. Unit-major layout (lane l=4j+q = gate q of
// unit j), 4 elements per wave, 1024 waves = 1 wave/SIMD. Latency-bound:
// wall = T * L_chain. R8 measured L~200cy. R9 folds: h is NEVER materialized
// on the chain -- gp_{t+1} = s + sum_r b_r * ror_r(r2) with s, b_r computed
// from o (available ~70cy before r2, during the tanh stall). Chain:
// ror(r2) -> fma tree -> exp2 -> +1 -> rcp -> quad_perm gather -> c fma ->
// exp2 -> +1 -> rcp (~176-182cy). The four serial trans latencies (~130cy)
// are the algorithmic floor; glue is now ~50cy.
// Lessons: TLP can't win (2I=212>L, R5/R6); per-lane gate replication goes
// issue-bound (R7); same-wave ILP interleave gets re-serialized (R3/R4).

static constexpr int T_STEPS = 2048;
static constexpr int CHUNK   = 16;              // timesteps per x-staging chunk
static constexpr int NCHUNK  = T_STEPS / CHUNK; // 128

template<int CTRL>
__device__ __forceinline__ float dpp_f(float v) {
    return __int_as_float(__builtin_amdgcn_update_dpp(
        0, __float_as_int(v), CTRL, 0xF, 0xF, false));
}

struct Ctx {
    float wih0, wih1, wih2;     // own row (gate q, unit j) w_ih, m_q-folded
    float W0, W1, W2, W3;       // m_q-folded w_hh row, columns in ror order
    float Wn0, Wn1, Wn2, Wn3;   // -0.5 * W_r (for the s accumulation)
};

// Recurrent state. r2 = rcp(1+2^{c'}), cp = -2.885*c, o2 = 2*o_gate,
// s/b0..b3 = next gate-preactivation affine form: gp = s + sum b_r*ror_r(r2).
struct St {
    float r2, cp, o2;
    float s, b0, b1, b2, b3;
};

template<int J>
__device__ __forceinline__ float comp(const float4& v) {
    if constexpr (J == 0) return v.x;
    else if constexpr (J == 1) return v.y;
    else if constexpr (J == 2) return v.z;
    else return v.w;
}

// xp[TT] = m_q * (w_ih[own row] . x_t) for 16 staged steps (off-chain)
template<int TT>
__device__ __forceinline__ void projx16(float (&xp)[CHUNK], const float4 (&bf)[12],
                                        const Ctx& k) {
    constexpr int j0 = 3 * TT, j1 = j0 + 1, j2 = j0 + 2;
    float x0 = comp<(j0 & 3)>(bf[j0 >> 2]);
    float x1 = comp<(j1 & 3)>(bf[j1 >> 2]);
    float x2 = comp<(j2 & 3)>(bf[j2 >> 2]);
    xp[TT] = fmaf(x0, k.wih0, fmaf(x1, k.wih1, x2 * k.wih2));
    if constexpr (TT + 1 < CHUNK) projx16<TT + 1>(xp, bf, k);
}

// One step. xpn = the NEXT step's projection (consumed by the s-precompute).
__device__ __forceinline__ void lstm_step(float xpn, St& S, const Ctx& k) {
    // ---- chain: gate preactivation directly from r2 (h never formed) ----
    float r21 = dpp_f<0x124>(S.r2);        // row_ror:4
    float r22 = dpp_f<0x128>(S.r2);        // row_ror:8
    float r23 = dpp_f<0x12C>(S.r2);        // row_ror:12
    float p   = fmaf(S.b0, S.r2, S.s);
    p         = fmaf(S.b1, r21, p);
    float q   = S.b2 * r22;
    q         = fmaf(S.b3, r23, q);
    float gp  = p + q;                     // m_q-scaled preactivation
    float e   = __builtin_amdgcn_exp2f(gp);
    float r   = __builtin_amdgcn_rcpf(1.0f + e);   // raw sigmoid (g-lane: sig(2x))
    // ---- gather i,f,g,o within the quad; c update ----
    float rg  = dpp_f<0xAA>(r);
    float rf  = dpp_f<0x55>(r);
    float ri  = dpp_f<0x00>(r);
    float ro  = dpp_f<0xFF>(r);
    float t   = fmaf(rg, -5.770780163555854f, 2.885390081777927f); // -2.885*tanh(g)
    float fc  = rf * S.cp;
    float cn  = fmaf(ri, t, fc);           // cp_new = -2.885*c_new
    S.cp = cn;
    float e2  = __builtin_amdgcn_exp2f(cn);    // tanh-side exp2: issue ASAP
    // ---- off-chain (issues during the tanh stall): next-step coeffs ----
    float o2  = ro + ro;
    float o21 = dpp_f<0x124>(o2);
    float o22 = dpp_f<0x128>(o2);
    float o23 = dpp_f<0x12C>(o2);
    S.b0 = k.W0 * o2;
    S.b1 = k.W1 * o21;
    S.b2 = k.W2 * o22;
    S.b3 = k.W3 * o23;
    float s = fmaf(k.Wn0, o2,  xpn);
    s       = fmaf(k.Wn1, o21, s);
    s       = fmaf(k.Wn2, o22, s);
    s       = fmaf(k.Wn3, o23, s);
    S.s  = s;
    S.o2 = o2;
    // ---- chain tail ----
    S.r2 = __builtin_amdgcn_rcpf(1.0f + e2);
}

// 16 steps; xpn of the last step comes from the NEXT chunk's xp[0] (xq).
template<int TT>
__device__ __forceinline__ void steps16(const float (&xp)[CHUNK], float xq,
                                        St& S, const Ctx& k) {
    lstm_step((TT + 1 < CHUNK) ? xp[TT + 1] : xq, S, k);
    if constexpr (TT + 1 < CHUNK) steps16<TT + 1>(xp, xq, S, k);
}

__device__ __forceinline__ void loadbf(float4 (&bf)[12], const float4* p) {
    #pragma unroll
    for (int i = 0; i < 12; ++i) bf[i] = p[i];
}

__global__ __launch_bounds__(256, 1) void lstm_kernel(
    const float* __restrict__ x,
    const float* __restrict__ w_ih,
    const float* __restrict__ w_hh,
    const float* __restrict__ fc_w,
    const float* __restrict__ fc_b,
    float* __restrict__ out)
{
    const int tid = threadIdx.x;
    const int l16 = tid & 15;
    const int b   = blockIdx.x * 16 + (tid >> 4);
    const int q   = l16 & 3;    // gate (0=i 1=f 2=g 3=o)
    const int j   = l16 >> 2;   // unit

    // probe row_ror direction: ror4 brings lane l-4 (dir A) or l+4 (dir B)
    float t1p = dpp_f<0x124>((float)l16);
    const bool dirB = (t1p == (float)((l16 + 4) & 15));

    const int row = 4 * q + j;  // PyTorch row = gate*H + unit
    const float mq = (q == 2) ? -2.885390081777927f : -1.4426950408889634f;

    Ctx k;
    k.wih0 = mq * w_ih[row * 3 + 0];
    k.wih1 = mq * w_ih[row * 3 + 1];
    k.wih2 = mq * w_ih[row * 3 + 2];
    {   // ror r brings unit (j -/+ r)'s value; fold into column order
        const int u1 = (j + (dirB ? 1 : -1) + 4) & 3;
        const int u2 = (j + (dirB ? 2 : -2) + 4) & 3;
        const int u3 = (j + (dirB ? 3 : -3) + 4) & 3;
        k.W0 = mq * w_hh[row * 4 + j];
        k.W1 = mq * w_hh[row * 4 + u1];
        k.W2 = mq * w_hh[row * 4 + u2];
        k.W3 = mq * w_hh[row * 4 + u3];
    }
    k.Wn0 = -0.5f * k.W0;
    k.Wn1 = -0.5f * k.W1;
    k.Wn2 = -0.5f * k.W2;
    k.Wn3 = -0.5f * k.W3;

    const float4* xb4 = reinterpret_cast<const float4*>(x + (size_t)b * (T_STEPS * 3));

    float4 bfA[12], bfB[12];        // double-buffered raw x (48 floats = 16 steps)
    float  xpA[CHUNK], xpB[CHUNK];  // double-buffered own-row projections
    loadbf(bfA, xb4);
    loadbf(bfB, xb4 + 12);
    projx16<0>(xpA, bfA, k);

    St S;
    S.cp = 0.f;                 // c = 0
    S.r2 = 0.5f;                // rcp(1+2^0)
    S.o2 = 0.f;
    S.b0 = S.b1 = S.b2 = S.b3 = 0.f;   // h = 0 -> gate preact = xp only
    S.s  = xpA[0];

    for (int it = 0; it < NCHUNK / 2; ++it) {
        const int ca = (2 * it + 2 < NCHUNK) ? 2 * it + 2 : NCHUNK - 1;
        loadbf(bfA, xb4 + ca * 12);
        projx16<0>(xpB, bfB, k);           // chunk 2it+1 projections
        steps16<0>(xpA, xpB[0], S, k);     // chunk 2it

        const int cb = (2 * it + 3 < NCHUNK) ? 2 * it + 3 : NCHUNK - 1;
        loadbf(bfB, xb4 + cb * 12);
        projx16<0>(xpA, bfA, k);           // chunk 2it+2 projections
        steps16<0>(xpB, xpA[0], S, k);     // chunk 2it+1
    }

    // h_j = o * tanh(c) = o2*(r2 - 0.5); quad j holds h_j in all 4 lanes
    float h  = S.o2 * (S.r2 - 0.5f);
    float rr = h * fc_w[j];
    float s1 = rr + dpp_f<0x124>(rr);   // + ror4
    float s2 = s1 + dpp_f<0x128>(s1);   // + ror8 -> sum over all 4 quads
    if (l16 == 0) out[b] = s2 + fc_b[0];
}

extern "C" void kernel_launch(void* const* d_in, const int* in_sizes, int n_in,
                              void* d_out, int out_size, void* d_ws, size_t ws_size,
                              hipStream_t stream) {
    const float* x    = (const float*)d_in[0];
    const float* w_ih = (const float*)d_in[1];
    const float* w_hh = (const float*)d_in[2];
    const float* fc_w = (const float*)d_in[3];
    const float* fc_b = (const float*)d_in[4];
    float* out = (float*)d_out;

    dim3 grid(4096 / 16);   // 256 blocks -> 1 per CU
    dim3 block(256);        // 4 waves -> 1 wave per SIMD chip-wide
    hipLaunchKernelGGL(lstm_kernel, grid, block, 0, stream,
                       x, w_ih, w_hh, fc_w, fc_b, out);
}

// Round 10
// 168.637 us; speedup vs baseline: 1.1788x; 1.1788x over previous
//
#include <hip/hip_runtime.h>

// LSTM, B=4096, T=2048, IN=3, H=4. Unit-major layout (lane l=4j+q = gate q of
// unit j), 4 elems/wave, 1024 waves = 1 wave/SIMD. wall = T * L_chain (proven
// R2-R9); L = 4 serial trans (~132cy) + tree/gather glue. R10: R8 datapath
// unchanged, but the chunk-seam work (12 loads + 48 projection fmas, ~8cy/step
// of in-order issue on the chain) is moved INTO the exp2 stall windows: each
// step issues 1 float4 load + 3 proj fmas right after exp2(gp), pinned by
// sched_barrier(0) so the compiler can't hoist them above the exp2 (R9's
// failure mode). Second pin after e2 keeps o2/no in the tanh window.
// Lessons: TLP can't beat L (R5/R6); per-lane gate replication goes
// issue-bound (R7); unpinned "off-chain" algebra lands on-chain (R9).

static constexpr int T_STEPS = 2048;
static constexpr int CHUNK   = 16;              // timesteps per x-staging chunk
static constexpr int NCHUNK  = T_STEPS / CHUNK; // 128

template<int CTRL>
__device__ __forceinline__ float dpp_f(float v) {
    return __int_as_float(__builtin_amdgcn_update_dpp(
        0, __float_as_int(v), CTRL, 0xF, 0xF, false));
}

struct Ctx {
    float wih0, wih1, wih2;     // own row (gate q, unit j) w_ih, m_q-folded
    float W0, W1, W2, W3;       // m_q-folded w_hh row, columns in ror order
};

template<int J>
__device__ __forceinline__ float comp(const float4& v) {
    if constexpr (J == 0) return v.x;
    else if constexpr (J == 1) return v.y;
    else if constexpr (J == 2) return v.z;
    else return v.w;
}

// prologue-only batch projection (chunk 0)
template<int TT>
__device__ __forceinline__ void projx16(float (&xp)[CHUNK], const float4 (&bf)[12],
                                        const Ctx& k) {
    constexpr int j0 = 3 * TT, j1 = j0 + 1, j2 = j0 + 2;
    float x0 = comp<(j0 & 3)>(bf[j0 >> 2]);
    float x1 = comp<(j1 & 3)>(bf[j1 >> 2]);
    float x2 = comp<(j2 & 3)>(bf[j2 >> 2]);
    xp[TT] = fmaf(x0, k.wih0, fmaf(x1, k.wih1, x2 * k.wih2));
    if constexpr (TT + 1 < CHUNK) projx16<TT + 1>(xp, bf, k);
}

// One chunk of 16 steps. Per step TT: consume xpC[TT] on the chain; inside the
// exp2(gp) stall window, issue load #TT of the next-next chunk (into bfL) and
// compute projection TT of the next chunk (bfN -> xpN).
template<int TT>
__device__ __forceinline__ void steps16i(
    const float (&xpC)[CHUNK], float (&xpN)[CHUNK],
    const float4 (&bfN)[12], float4 (&bfL)[12], const float4* __restrict__ ldp,
    float& h, float& cp, const Ctx& k)
{
    // ---- chain head: h rotations + gate preactivation tree ----
    float h1 = dpp_f<0x124>(h);            // row_ror:4
    float h2 = dpp_f<0x128>(h);            // row_ror:8
    float h3 = dpp_f<0x12C>(h);            // row_ror:12
    float a  = fmaf(h,  k.W0, xpC[TT]);
    a        = fmaf(h1, k.W1, a);
    float bq = h2 * k.W2;
    bq       = fmaf(h3, k.W3, bq);
    float gp = a + bq;                     // m_q-scaled preactivation
    float e  = __builtin_amdgcn_exp2f(gp);
    __builtin_amdgcn_sched_barrier(0);
    // ---- exp2 stall window: staging work (off-chain by construction) ----
    if constexpr (TT < 12) bfL[TT] = ldp[TT];
    {
        constexpr int j0 = 3 * TT, j1 = j0 + 1, j2 = j0 + 2;
        float x0 = comp<(j0 & 3)>(bfN[j0 >> 2]);
        float x1 = comp<(j1 & 3)>(bfN[j1 >> 2]);
        float x2 = comp<(j2 & 3)>(bfN[j2 >> 2]);
        xpN[TT] = fmaf(x0, k.wih0, fmaf(x1, k.wih1, x2 * k.wih2));
    }
    // ---- chain: sigmoid, quad gather, c update ----
    float r  = __builtin_amdgcn_rcpf(1.0f + e);    // raw sigmoid (g-lane: sig(2x))
    float rg = dpp_f<0xAA>(r);
    float rf = dpp_f<0x55>(r);
    float ri = dpp_f<0x00>(r);
    float ro = dpp_f<0xFF>(r);
    float t  = fmaf(rg, -5.770780163555854f, 2.885390081777927f); // -2.885*tanh(g)
    float fc = rf * cp;
    float cn = fmaf(ri, t, fc);            // cp_new = -2.885*c_new
    cp = cn;
    float e2 = __builtin_amdgcn_exp2f(cn);
    __builtin_amdgcn_sched_barrier(0);
    // ---- tanh stall window: h-combine operands ----
    float o2 = ro + ro;
    float no = -ro;
    // ---- chain tail ----
    float r2 = __builtin_amdgcn_rcpf(1.0f + e2);
    h = fmaf(o2, r2, no);                  // h = o*(2*r2 - 1)
    if constexpr (TT + 1 < CHUNK)
        steps16i<TT + 1>(xpC, xpN, bfN, bfL, ldp, h, cp, k);
}

__device__ __forceinline__ void loadbf(float4 (&bf)[12], const float4* p) {
    #pragma unroll
    for (int i = 0; i < 12; ++i) bf[i] = p[i];
}

__global__ __launch_bounds__(256, 1) void lstm_kernel(
    const float* __restrict__ x,
    const float* __restrict__ w_ih,
    const float* __restrict__ w_hh,
    const float* __restrict__ fc_w,
    const float* __restrict__ fc_b,
    float* __restrict__ out)
{
    const int tid = threadIdx.x;
    const int l16 = tid & 15;
    const int b   = blockIdx.x * 16 + (tid >> 4);
    const int q   = l16 & 3;    // gate (0=i 1=f 2=g 3=o)
    const int j   = l16 >> 2;   // unit

    // probe row_ror direction: ror4 brings lane l-4 (dir A) or l+4 (dir B)
    float t1p = dpp_f<0x124>((float)l16);
    const bool dirB = (t1p == (float)((l16 + 4) & 15));

    const int row = 4 * q + j;  // PyTorch row = gate*H + unit
    const float mq = (q == 2) ? -2.885390081777927f : -1.4426950408889634f;

    Ctx k;
    k.wih0 = mq * w_ih[row * 3 + 0];
    k.wih1 = mq * w_ih[row * 3 + 1];
    k.wih2 = mq * w_ih[row * 3 + 2];
    {   // ror r brings unit (j -/+ r)'s value; fold into column order
        const int u1 = (j + (dirB ? 1 : -1) + 4) & 3;
        const int u2 = (j + (dirB ? 2 : -2) + 4) & 3;
        const int u3 = (j + (dirB ? 3 : -3) + 4) & 3;
        k.W0 = mq * w_hh[row * 4 + j];
        k.W1 = mq * w_hh[row * 4 + u1];
        k.W2 = mq * w_hh[row * 4 + u2];
        k.W3 = mq * w_hh[row * 4 + u3];
    }

    const float4* xb4 = reinterpret_cast<const float4*>(x + (size_t)b * (T_STEPS * 3));

    float4 bfA[12], bfB[12];        // double-buffered raw x (48 floats = 16 steps)
    float  xpA[CHUNK], xpB[CHUNK];  // double-buffered own-row projections
    loadbf(bfA, xb4);               // chunk 0 raw
    loadbf(bfB, xb4 + 12);          // chunk 1 raw
    projx16<0>(xpA, bfA, k);        // chunk 0 projections (prologue, off-chain)

    float h = 0.f, cp = 0.f;        // cp = -2.885*c

    for (int it = 0; it < NCHUNK / 2; ++it) {
        // half 1: consume chunk 2it (xpA); project chunk 2it+1 (bfB -> xpB);
        //         load chunk 2it+2 into bfA -- all inside stall windows
        const int ca = (2 * it + 2 < NCHUNK) ? 2 * it + 2 : NCHUNK - 1;
        steps16i<0>(xpA, xpB, bfB, bfA, xb4 + ca * 12, h, cp, k);
        // half 2: consume chunk 2it+1 (xpB); project chunk 2it+2 (bfA -> xpA);
        //         load chunk 2it+3 into bfB
        const int cb = (2 * it + 3 < NCHUNK) ? 2 * it + 3 : NCHUNK - 1;
        steps16i<0>(xpB, xpA, bfA, bfB, xb4 + cb * 12, h, cp, k);
    }

    // out[b] = fc_w . h + fc_b ; quad j holds h_j -> ror-sum across quads
    float rr = h * fc_w[j];
    float s1 = rr + dpp_f<0x124>(rr);   // + ror4
    float s2 = s1 + dpp_f<0x128>(s1);   // + ror8 -> sum over all 4 quads
    if (l16 == 0) out[b] = s2 + fc_b[0];
}

extern "C" void kernel_launch(void* const* d_in, const int* in_sizes, int n_in,
                              void* d_out, int out_size, void* d_ws, size_t ws_size,
                              hipStream_t stream) {
    const float* x    = (const float*)d_in[0];
    const float* w_ih = (const float*)d_in[1];
    const float* w_hh = (const float*)d_in[2];
    const float* fc_w = (const float*)d_in[3];
    const float* fc_b = (const float*)d_in[4];
    float* out = (float*)d_out;

    dim3 grid(4096 / 16);   // 256 blocks -> 1 per CU
    dim3 block(256);        // 4 waves -> 1 wave per SIMD chip-wide
    hipLaunchKernelGGL(lstm_kernel, grid, block, 0, stream,
                       x, w_ih, w_hh, fc_w, fc_b, out);
}